// Round 1
// baseline (324.073 us; speedup 1.0000x reference)
//
#include <hip/hip_runtime.h>

// Problem constants (GlobalPointer: B=16, L=512, H=1024, HEADS=12, D=64)
#define BB 16
#define LL 512
#define HH 1024
#define HEADS 12
#define DD 64
#define N1 1536   // HEADS * 2 * DD
#define M1 8192   // BB * LL
#define NEGC 1e12f

typedef short bf16x8 __attribute__((ext_vector_type(8)));
typedef float f32x4 __attribute__((ext_vector_type(4)));

__device__ __forceinline__ unsigned short f2bf(float f) {
    union { float f; unsigned int u; } v; v.f = f;
    unsigned int u = v.u;
    return (unsigned short)((u + 0x7fffu + ((u >> 16) & 1u)) >> 16);
}

// ---------------- Kernel 1: X fp32 -> bf16 (8192x1024) ----------------
__global__ __launch_bounds__(256) void k_conv_x(const float* __restrict__ X,
                                                unsigned short* __restrict__ Xb,
                                                int n4) {
    int i = blockIdx.x * 256 + threadIdx.x;
    if (i >= n4) return;
    float4 v = ((const float4*)X)[i];
    ushort4 o;
    o.x = f2bf(v.x); o.y = f2bf(v.y); o.z = f2bf(v.z); o.w = f2bf(v.w);
    ((ushort4*)Xb)[i] = o;
}

// ------------- Kernel 2: W (1024x1536 f32) -> Wt (1536x1024 bf16) -------------
__global__ __launch_bounds__(256) void k_trans_w(const float* __restrict__ W,
                                                 unsigned short* __restrict__ Wt) {
    __shared__ float tile[32][33];
    int n0 = blockIdx.x * 32;
    int k0 = blockIdx.y * 32;
    int tx = threadIdx.x;   // 0..31
    int ty = threadIdx.y;   // 0..7
#pragma unroll
    for (int i = 0; i < 4; i++) {
        int k = ty + i * 8;
        tile[k][tx] = W[(size_t)(k0 + k) * N1 + n0 + tx];
    }
    __syncthreads();
#pragma unroll
    for (int i = 0; i < 4; i++) {
        int n = ty + i * 8;
        Wt[(size_t)(n0 + n) * HH + k0 + tx] = f2bf(tile[tx][n]);
    }
}

// ------------- Kernel 3: C = Xb @ Wt^T (+bias, RoPE) -> Qr, Kr (bf16) -------------
// Block: 64(m) x 64(n) tile, 256 threads = 4 waves, each wave 32x32 (2x2 MFMA tiles).
// MFMA 16x16x32 bf16. A-frag: A[m=lane&15][k=quad*8+j]; B-frag: B^T rows the same.
// D: col=lane&15, row=quad*4+reg.
__global__ __launch_bounds__(256) void k_gemm1_rope(
    const unsigned short* __restrict__ Xb,   // [8192][1024]
    const unsigned short* __restrict__ Wt,   // [1536][1024]
    const float* __restrict__ bias,          // [1536]
    const float* __restrict__ pe,            // [512][64]  pe[l][2i]=sin, [2i+1]=cos
    unsigned short* __restrict__ Qr,         // [B*HEADS*512][64]
    unsigned short* __restrict__ Kr)
{
    __shared__ __align__(16) unsigned short As[64 * 40];
    __shared__ __align__(16) unsigned short Bs[64 * 40];
    int m0 = blockIdx.y * 64;
    int n0 = blockIdx.x * 64;
    int tid = threadIdx.x;
    int w  = tid >> 6;
    int ln = tid & 63;
    int lq = ln >> 4;
    int lm = ln & 15;
    int mw = (w & 1) * 32;
    int nw = (w >> 1) * 32;

    int srow = tid >> 2;          // 0..63
    int scol = (tid & 3) * 8;     // 0,8,16,24

    f32x4 acc[2][2] = {};

    for (int kk = 0; kk < HH; kk += 32) {
        uint4 av = *(const uint4*)&Xb[(size_t)(m0 + srow) * HH + kk + scol];
        uint4 bv = *(const uint4*)&Wt[(size_t)(n0 + srow) * HH + kk + scol];
        *(uint4*)&As[srow * 40 + scol] = av;
        *(uint4*)&Bs[srow * 40 + scol] = bv;
        __syncthreads();
        bf16x8 af0 = *(const bf16x8*)&As[(mw + lm) * 40 + lq * 8];
        bf16x8 af1 = *(const bf16x8*)&As[(mw + 16 + lm) * 40 + lq * 8];
        bf16x8 bf0 = *(const bf16x8*)&Bs[(nw + lm) * 40 + lq * 8];
        bf16x8 bf1 = *(const bf16x8*)&Bs[(nw + 16 + lm) * 40 + lq * 8];
        acc[0][0] = __builtin_amdgcn_mfma_f32_16x16x32_bf16(af0, bf0, acc[0][0], 0, 0, 0);
        acc[0][1] = __builtin_amdgcn_mfma_f32_16x16x32_bf16(af0, bf1, acc[0][1], 0, 0, 0);
        acc[1][0] = __builtin_amdgcn_mfma_f32_16x16x32_bf16(af1, bf0, acc[1][0], 0, 0, 0);
        acc[1][1] = __builtin_amdgcn_mfma_f32_16x16x32_bf16(af1, bf1, acc[1][1], 0, 0, 0);
        __syncthreads();
    }

    // Epilogue: bias + interleaved RoPE, scatter to Qr/Kr as bf16.
#pragma unroll
    for (int nt = 0; nt < 2; nt++) {
        int n = n0 + nw + nt * 16 + lm;        // 0..1535
        float bv = bias[n];
        int h = n >> 7;                         // head
        int c = n & 127;                        // channel in [0,128)
        int j = c & 63;                         // d-index
        int ii = j >> 1;                        // freq index
        bool isK = (c >= 64);
#pragma unroll
        for (int mt = 0; mt < 2; mt++) {
#pragma unroll
            for (int r = 0; r < 4; r++) {
                int m = m0 + mw + mt * 16 + lq * 4 + r;   // 0..8191
                int l = m & (LL - 1);
                int bidx = m >> 9;
                float v = acc[mt][nt][r] + bv;
                float vp = __shfl_xor(v, 1, 64);          // pair partner (n^1 == lane^1)
                float sv = pe[l * 64 + 2 * ii];
                float cv = pe[l * 64 + 2 * ii + 1];
                float o = (j & 1) ? (v * cv + vp * sv) : (v * cv - vp * sv);
                unsigned short ob = f2bf(o);
                size_t idx = ((size_t)(bidx * HEADS + h) * LL + l) * DD + j;
                if (isK) Kr[idx] = ob; else Qr[idx] = ob;
            }
        }
    }
}

// ------------- Kernel 4: logits = Q @ K^T, mask, /8 -------------
// Per (b,h): 512x512, K-dim 64. Block 64x64 tile.
__global__ __launch_bounds__(256) void k_gemm2(
    const unsigned short* __restrict__ Qr,
    const unsigned short* __restrict__ Kr,
    const int* __restrict__ mask,            // [B][L]
    float* __restrict__ out)                 // [B][HEADS][L][L]
{
    __shared__ __align__(16) unsigned short Qs[64 * 72];
    __shared__ __align__(16) unsigned short Ks[64 * 72];
    int bh = blockIdx.z;
    int b  = bh / HEADS;
    int n0 = blockIdx.x * 64;
    int m0 = blockIdx.y * 64;
    int tid = threadIdx.x;
    int w  = tid >> 6;
    int ln = tid & 63;
    int lq = ln >> 4;
    int lm = ln & 15;
    int mw = (w & 1) * 32;
    int nw = (w >> 1) * 32;

    const unsigned short* Qb = Qr + (size_t)bh * LL * DD;
    const unsigned short* Kb = Kr + (size_t)bh * LL * DD;

    int srow = tid >> 3;          // 0..31
    int scol = (tid & 7) * 8;     // 0..56
#pragma unroll
    for (int p = 0; p < 2; p++) {
        int row = srow + p * 32;
        *(uint4*)&Qs[row * 72 + scol] = *(const uint4*)&Qb[(size_t)(m0 + row) * DD + scol];
        *(uint4*)&Ks[row * 72 + scol] = *(const uint4*)&Kb[(size_t)(n0 + row) * DD + scol];
    }
    __syncthreads();

    f32x4 acc[2][2] = {};
#pragma unroll
    for (int kk = 0; kk < 64; kk += 32) {
        bf16x8 a0 = *(const bf16x8*)&Qs[(mw + lm) * 72 + kk + lq * 8];
        bf16x8 a1 = *(const bf16x8*)&Qs[(mw + 16 + lm) * 72 + kk + lq * 8];
        bf16x8 b0 = *(const bf16x8*)&Ks[(nw + lm) * 72 + kk + lq * 8];
        bf16x8 b1 = *(const bf16x8*)&Ks[(nw + 16 + lm) * 72 + kk + lq * 8];
        acc[0][0] = __builtin_amdgcn_mfma_f32_16x16x32_bf16(a0, b0, acc[0][0], 0, 0, 0);
        acc[0][1] = __builtin_amdgcn_mfma_f32_16x16x32_bf16(a0, b1, acc[0][1], 0, 0, 0);
        acc[1][0] = __builtin_amdgcn_mfma_f32_16x16x32_bf16(a1, b0, acc[1][0], 0, 0, 0);
        acc[1][1] = __builtin_amdgcn_mfma_f32_16x16x32_bf16(a1, b1, acc[1][1], 0, 0, 0);
    }

#pragma unroll
    for (int nt = 0; nt < 2; nt++) {
        int n = n0 + nw + nt * 16 + lm;
        float pm = (float)mask[b * LL + n];
        float negn = (1.0f - pm) * NEGC;
#pragma unroll
        for (int mt = 0; mt < 2; mt++) {
#pragma unroll
            for (int r = 0; r < 4; r++) {
                int m = m0 + mw + mt * 16 + lq * 4 + r;
                float dot = acc[mt][nt][r];
                float val = (dot * pm - negn - (n < m ? NEGC : 0.0f)) * 0.125f;
                out[((size_t)bh * LL + m) * LL + n] = val;
            }
        }
    }
}

extern "C" void kernel_launch(void* const* d_in, const int* in_sizes, int n_in,
                              void* d_out, int out_size, void* d_ws, size_t ws_size,
                              hipStream_t stream) {
    const float* X    = (const float*)d_in[0];   // (16,512,1024)
    const int*   mask = (const int*)d_in[1];     // (16,512)
    const float* W    = (const float*)d_in[2];   // (1024,1536)
    const float* bias = (const float*)d_in[3];   // (1536,)
    const float* pe   = (const float*)d_in[4];   // (512,64)
    float* out = (float*)d_out;

    char* ws = (char*)d_ws;
    unsigned short* Xb = (unsigned short*)ws;                                // 16.78 MB
    unsigned short* Wt = (unsigned short*)(ws + 16777216);                   // 3.15 MB
    unsigned short* Qr = (unsigned short*)(ws + 16777216 + 3145728);         // 12.58 MB
    unsigned short* Kr = Qr + (size_t)BB * HEADS * LL * DD;                  // 12.58 MB

    // 1) convert X to bf16
    k_conv_x<<<dim3((M1 * HH / 4 + 255) / 256), dim3(256), 0, stream>>>(X, Xb, M1 * HH / 4);
    // 2) transpose+convert W
    k_trans_w<<<dim3(N1 / 32, HH / 32), dim3(32, 8), 0, stream>>>(W, Wt);
    // 3) GEMM1 + bias + RoPE -> Qr, Kr
    k_gemm1_rope<<<dim3(N1 / 64, M1 / 64), dim3(256), 0, stream>>>(Xb, Wt, bias, pe, Qr, Kr);
    // 4) GEMM2 + mask + scale -> out
    k_gemm2<<<dim3(LL / 64, LL / 64, BB * HEADS), dim3(256), 0, stream>>>(Qr, Kr, mask, out);
}